// Round 2
// baseline (3406.237 us; speedup 1.0000x reference)
//
#include <hip/hip_runtime.h>

#define NN 100000
#define NE 3200000
#define NF 512
#define NH 128
#define NK 10

// ---------------- CSR build ----------------

__global__ void count_kernel(const int* __restrict__ col, int* __restrict__ cnt) {
  int e = blockIdx.x * 256 + threadIdx.x;
  if (e < NE) atomicAdd(&cnt[col[e]], 1);
}

__global__ void dinv_kernel(const int* __restrict__ cnt, float* __restrict__ dinv) {
  int i = blockIdx.x * 256 + threadIdx.x;
  if (i < NN) dinv[i] = rsqrtf((float)(cnt[i] + 1));
}

__global__ __launch_bounds__(1024) void scan_kernel(const int* __restrict__ cnt,
                                                    int* __restrict__ colptr,
                                                    int* __restrict__ cursor) {
  __shared__ int buf[1024];
  __shared__ int carry;
  int t = threadIdx.x;
  if (t == 0) carry = 0;
  __syncthreads();
  for (int base = 0; base < NN; base += 1024) {
    int i = base + t;
    int v = (i < NN) ? cnt[i] : 0;
    buf[t] = v;
    __syncthreads();
    for (int off = 1; off < 1024; off <<= 1) {
      int add = (t >= off) ? buf[t - off] : 0;
      __syncthreads();
      buf[t] += add;
      __syncthreads();
    }
    int incl = buf[t];
    int c = carry;
    if (i < NN) {
      colptr[i] = c + incl - v;
      cursor[i] = c + incl - v;
    }
    __syncthreads();
    if (t == 1023) carry = c + incl;
    __syncthreads();
  }
  if (t == 0) colptr[NN] = carry;
}

__global__ void fill_kernel(const int* __restrict__ row, const int* __restrict__ col,
                            const float* __restrict__ dinv, int* __restrict__ cursor,
                            int* __restrict__ erow, float* __restrict__ enorm) {
  int e = blockIdx.x * 256 + threadIdx.x;
  if (e >= NE) return;
  int r = row[e], c = col[e];
  int pos = atomicAdd(&cursor[c], 1);
  erow[pos] = r;
  enorm[pos] = dinv[r] * dinv[c];
}

// ---------------- GEMMs ----------------
// Tile: 64 rows x 128 cols, 256 threads, each thread 4 rows x 8 cols.

__global__ __launch_bounds__(256) void gemm1_kernel(
    const float* __restrict__ X, const float* __restrict__ W,
    const float* __restrict__ bias, float* __restrict__ out) {
  __shared__ float xs[32][68];   // [k][row] transposed, row padded 64->68
  __shared__ float ws[32][132];  // [k][col], col padded 128->132
  int tid = threadIdx.x;
  int tx = tid & 15;
  int ty = tid >> 4;
  int row0 = blockIdx.x * 64;
  float acc[4][8];
#pragma unroll
  for (int r = 0; r < 4; ++r)
#pragma unroll
    for (int c = 0; c < 8; ++c) acc[r][c] = 0.f;

  for (int k0 = 0; k0 < NF; k0 += 32) {
    // X tile: 64 rows x 32 k, stored transposed
#pragma unroll
    for (int i = 0; i < 2; ++i) {
      int slot = tid + i * 256;      // 512 slots of 4 floats
      int r = slot >> 3;
      int q = slot & 7;
      int grow = row0 + r;
      float4 v = make_float4(0.f, 0.f, 0.f, 0.f);
      if (grow < NN) v = *((const float4*)(X + (size_t)grow * NF + k0 + q * 4));
      xs[q * 4 + 0][r] = v.x;
      xs[q * 4 + 1][r] = v.y;
      xs[q * 4 + 2][r] = v.z;
      xs[q * 4 + 3][r] = v.w;
    }
    // W tile: 32 k x 128 cols
#pragma unroll
    for (int i = 0; i < 4; ++i) {
      int slot = tid + i * 256;      // 1024 slots of 4 floats
      int kr = slot >> 5;
      int q = slot & 31;
      float4 v = *((const float4*)(W + (size_t)(k0 + kr) * NH + q * 4));
      ws[kr][q * 4 + 0] = v.x;
      ws[kr][q * 4 + 1] = v.y;
      ws[kr][q * 4 + 2] = v.z;
      ws[kr][q * 4 + 3] = v.w;
    }
    __syncthreads();
#pragma unroll
    for (int kk = 0; kk < 32; ++kk) {
      float4 a = *((const float4*)&xs[kk][ty * 4]);
      float4 b0 = *((const float4*)&ws[kk][tx * 8]);
      float4 b1 = *((const float4*)&ws[kk][tx * 8 + 4]);
      float av[4] = {a.x, a.y, a.z, a.w};
      float bv[8] = {b0.x, b0.y, b0.z, b0.w, b1.x, b1.y, b1.z, b1.w};
#pragma unroll
      for (int r = 0; r < 4; ++r)
#pragma unroll
        for (int c = 0; c < 8; ++c) acc[r][c] = fmaf(av[r], bv[c], acc[r][c]);
    }
    __syncthreads();
  }
#pragma unroll
  for (int r = 0; r < 4; ++r) {
    int grow = row0 + ty * 4 + r;
    if (grow < NN) {
#pragma unroll
      for (int c = 0; c < 8; ++c) {
        int gc = tx * 8 + c;
        float v = acc[r][c] + bias[gc];
        out[(size_t)grow * NH + gc] = fmaxf(v, 0.f);
      }
    }
  }
}

__global__ __launch_bounds__(256) void gemm2_kernel(
    const float* __restrict__ X, const float* __restrict__ W,
    const float* __restrict__ bias, float* __restrict__ hout,
    float* __restrict__ accb, const float* __restrict__ temp) {
  __shared__ float xs[32][68];
  __shared__ float ws[32][132];
  int tid = threadIdx.x;
  int tx = tid & 15;
  int ty = tid >> 4;
  int row0 = blockIdx.x * 64;
  float acc[4][8];
#pragma unroll
  for (int r = 0; r < 4; ++r)
#pragma unroll
    for (int c = 0; c < 8; ++c) acc[r][c] = 0.f;

  for (int k0 = 0; k0 < NH; k0 += 32) {
#pragma unroll
    for (int i = 0; i < 2; ++i) {
      int slot = tid + i * 256;
      int r = slot >> 3;
      int q = slot & 7;
      int grow = row0 + r;
      float4 v = make_float4(0.f, 0.f, 0.f, 0.f);
      if (grow < NN) v = *((const float4*)(X + (size_t)grow * NH + k0 + q * 4));
      xs[q * 4 + 0][r] = v.x;
      xs[q * 4 + 1][r] = v.y;
      xs[q * 4 + 2][r] = v.z;
      xs[q * 4 + 3][r] = v.w;
    }
#pragma unroll
    for (int i = 0; i < 4; ++i) {
      int slot = tid + i * 256;
      int kr = slot >> 5;
      int q = slot & 31;
      float4 v = *((const float4*)(W + (size_t)(k0 + kr) * NH + q * 4));
      ws[kr][q * 4 + 0] = v.x;
      ws[kr][q * 4 + 1] = v.y;
      ws[kr][q * 4 + 2] = v.z;
      ws[kr][q * 4 + 3] = v.w;
    }
    __syncthreads();
#pragma unroll
    for (int kk = 0; kk < 32; ++kk) {
      float4 a = *((const float4*)&xs[kk][ty * 4]);
      float4 b0 = *((const float4*)&ws[kk][tx * 8]);
      float4 b1 = *((const float4*)&ws[kk][tx * 8 + 4]);
      float av[4] = {a.x, a.y, a.z, a.w};
      float bv[8] = {b0.x, b0.y, b0.z, b0.w, b1.x, b1.y, b1.z, b1.w};
#pragma unroll
      for (int r = 0; r < 4; ++r)
#pragma unroll
        for (int c = 0; c < 8; ++c) acc[r][c] = fmaf(av[r], bv[c], acc[r][c]);
    }
    __syncthreads();
  }
  float t0 = temp[0];
#pragma unroll
  for (int r = 0; r < 4; ++r) {
    int grow = row0 + ty * 4 + r;
    if (grow < NN) {
#pragma unroll
      for (int c = 0; c < 8; ++c) {
        int gc = tx * 8 + c;
        float v = acc[r][c] + bias[gc];
        hout[(size_t)grow * NH + gc] = v;
        accb[(size_t)grow * NH + gc] = t0 * v;
      }
    }
  }
}

// ---------------- Propagation: one wave per node ----------------

__global__ __launch_bounds__(256) void prop_kernel(
    const float* __restrict__ src, float* __restrict__ dst,
    float* __restrict__ acc, const float* __restrict__ dinv,
    const int* __restrict__ colptr, const int* __restrict__ erow,
    const float* __restrict__ enorm, const float* __restrict__ temp, int step) {
  int wave = threadIdx.x >> 6;
  int lane = threadIdx.x & 63;
  int node = blockIdx.x * 4 + wave;
  if (node >= NN) return;
  float gamma = temp[step + 1];
  int beg = colptr[node];
  int end = colptr[node + 1];
  const float2* s2 = (const float2*)src;
  float ax = 0.f, ay = 0.f;
  for (int base = beg; base < end; base += 64) {
    int idx = base + lane;
    int r = 0;
    float wgt = 0.f;
    if (idx < end) {
      r = erow[idx];
      // defensive clamp: an index bug shows as finite wrong values, not NaN/fault
      r = (r < 0) ? 0 : ((r >= NN) ? NN - 1 : r);
      wgt = enorm[idx];
    }
    int m = end - base;
    if (m > 64) m = 64;
    for (int j = 0; j < m; ++j) {
      int rj = __shfl(r, j);
      float wj = __shfl(wgt, j);
      float2 v = s2[(size_t)rj * 64 + lane];
      ax = fmaf(wj, v.x, ax);
      ay = fmaf(wj, v.y, ay);
    }
  }
  // self loop
  float di = dinv[node];
  float sw = di * di;
  float2 vs = s2[(size_t)node * 64 + lane];
  ax = fmaf(sw, vs.x, ax);
  ay = fmaf(sw, vs.y, ay);
  float2 o;
  o.x = ax;
  o.y = ay;
  ((float2*)dst)[(size_t)node * 64 + lane] = o;
  float2* a2 = (float2*)acc;
  float2 av = a2[(size_t)node * 64 + lane];
  av.x = fmaf(gamma, ax, av.x);
  av.y = fmaf(gamma, ay, av.y);
  a2[(size_t)node * 64 + lane] = av;
}

// ---------------- launch ----------------

extern "C" void kernel_launch(void* const* d_in, const int* in_sizes, int n_in,
                              void* d_out, int out_size, void* d_ws, size_t ws_size,
                              hipStream_t stream) {
  const float* x = (const float*)d_in[0];
  const int* erow_in = (const int*)d_in[1];          // edge_index[0], E ints
  const int* ecol_in = erow_in + NE;                 // edge_index[1]
  const float* W1 = (const float*)d_in[2];
  const float* b1 = (const float*)d_in[3];
  const float* W2 = (const float*)d_in[4];
  const float* b2 = (const float*)d_in[5];
  const float* temp = (const float*)d_in[6];

  char* w = (char*)d_ws;
  size_t o = 0;
  auto alloc = [&](size_t bytes) -> void* {
    void* p = w + o;
    o += (bytes + 255) & ~(size_t)255;
    return p;
  };
  int* cnt = (int*)alloc((size_t)NN * 4);
  int* colptr = (int*)alloc((size_t)(NN + 1) * 4);
  int* cursor = (int*)alloc((size_t)NN * 4);
  float* dinv = (float*)alloc((size_t)NN * 4);
  int* erow = (int*)alloc((size_t)NE * 4);
  float* enorm = (float*)alloc((size_t)NE * 4);
  float* bufA = (float*)alloc((size_t)NN * NH * 4);
  float* bufB = (float*)alloc((size_t)NN * NH * 4);
  float* accb = (float*)d_out;  // accumulate PPR sum directly in output (fp32)
  (void)ws_size;

  hipMemsetAsync(cnt, 0, (size_t)NN * 4, stream);

  count_kernel<<<NE / 256, 256, 0, stream>>>(ecol_in, cnt);
  dinv_kernel<<<(NN + 255) / 256, 256, 0, stream>>>(cnt, dinv);
  scan_kernel<<<1, 1024, 0, stream>>>(cnt, colptr, cursor);
  fill_kernel<<<NE / 256, 256, 0, stream>>>(erow_in, ecol_in, dinv, cursor, erow, enorm);

  gemm1_kernel<<<(NN + 63) / 64, 256, 0, stream>>>(x, W1, b1, bufA);
  gemm2_kernel<<<(NN + 63) / 64, 256, 0, stream>>>(bufA, W2, b2, bufB, accb, temp);

  float* src = bufB;
  float* dst = bufA;
  for (int k = 0; k < NK; ++k) {
    prop_kernel<<<(NN + 3) / 4, 256, 0, stream>>>(src, dst, accb, dinv, colptr, erow,
                                                  enorm, temp, k);
    float* t = src;
    src = dst;
    dst = t;
  }
}

// Round 3
// 2261.833 us; speedup vs baseline: 1.5060x; 1.5060x over previous
//
#include <hip/hip_runtime.h>

#define NN 100000
#define NE 3200000
#define NF 512
#define NH 128
#define NK 10

typedef unsigned short u16;
typedef unsigned int u32;

__device__ __forceinline__ float bf2f(u32 lo16) {
  return __uint_as_float(lo16 << 16);
}
__device__ __forceinline__ u32 f2bf(float f) {
  u32 x = __float_as_uint(f);
  return (x + 0x7fffu + ((x >> 16) & 1u)) >> 16;  // RNE
}
__device__ __forceinline__ u32 pack2(float a, float b) {
  return f2bf(a) | (f2bf(b) << 16);
}

// ---------------- CSR build ----------------

__global__ void count_kernel(const int* __restrict__ col, int* __restrict__ cnt) {
  int e = blockIdx.x * 256 + threadIdx.x;
  if (e < NE) atomicAdd(&cnt[col[e]], 1);
}

__global__ void dinv_kernel(const int* __restrict__ cnt, float* __restrict__ dinv) {
  int i = blockIdx.x * 256 + threadIdx.x;
  if (i < NN) dinv[i] = rsqrtf((float)(cnt[i] + 1));
}

__global__ __launch_bounds__(1024) void scan_kernel(const int* __restrict__ cnt,
                                                    int* __restrict__ colptr,
                                                    int* __restrict__ cursor) {
  __shared__ int buf[1024];
  __shared__ int carry;
  int t = threadIdx.x;
  if (t == 0) carry = 0;
  __syncthreads();
  for (int base = 0; base < NN; base += 1024) {
    int i = base + t;
    int v = (i < NN) ? cnt[i] : 0;
    buf[t] = v;
    __syncthreads();
    for (int off = 1; off < 1024; off <<= 1) {
      int add = (t >= off) ? buf[t - off] : 0;
      __syncthreads();
      buf[t] += add;
      __syncthreads();
    }
    int incl = buf[t];
    int c = carry;
    if (i < NN) {
      colptr[i] = c + incl - v;
      cursor[i] = c + incl - v;
    }
    __syncthreads();
    if (t == 1023) carry = c + incl;
    __syncthreads();
  }
  if (t == 0) colptr[NN] = carry;
}

__global__ void fill_kernel(const int* __restrict__ row, const int* __restrict__ col,
                            const float* __restrict__ dinv, int* __restrict__ cursor,
                            int2* __restrict__ epack) {
  int e = blockIdx.x * 256 + threadIdx.x;
  if (e >= NE) return;
  int r = row[e], c = col[e];
  int pos = atomicAdd(&cursor[c], 1);
  int2 p;
  p.x = r;
  p.y = __float_as_int(dinv[r] * dinv[c]);
  epack[pos] = p;
}

// ---------------- GEMMs ----------------
// Tile: 64 rows x 128 cols, 256 threads, each thread 4 rows x 8 cols.

__global__ __launch_bounds__(256) void gemm1_kernel(
    const float* __restrict__ X, const float* __restrict__ W,
    const float* __restrict__ bias, float* __restrict__ out) {
  __shared__ float xs[32][68];   // [k][row] transposed, row padded 64->68
  __shared__ float ws[32][132];  // [k][col], col padded 128->132
  int tid = threadIdx.x;
  int tx = tid & 15;
  int ty = tid >> 4;
  int row0 = blockIdx.x * 64;
  float acc[4][8];
#pragma unroll
  for (int r = 0; r < 4; ++r)
#pragma unroll
    for (int c = 0; c < 8; ++c) acc[r][c] = 0.f;

  for (int k0 = 0; k0 < NF; k0 += 32) {
#pragma unroll
    for (int i = 0; i < 2; ++i) {
      int slot = tid + i * 256;      // 512 slots of 4 floats
      int r = slot >> 3;
      int q = slot & 7;
      int grow = row0 + r;
      float4 v = make_float4(0.f, 0.f, 0.f, 0.f);
      if (grow < NN) v = *((const float4*)(X + (size_t)grow * NF + k0 + q * 4));
      xs[q * 4 + 0][r] = v.x;
      xs[q * 4 + 1][r] = v.y;
      xs[q * 4 + 2][r] = v.z;
      xs[q * 4 + 3][r] = v.w;
    }
#pragma unroll
    for (int i = 0; i < 4; ++i) {
      int slot = tid + i * 256;      // 1024 slots of 4 floats
      int kr = slot >> 5;
      int q = slot & 31;
      float4 v = *((const float4*)(W + (size_t)(k0 + kr) * NH + q * 4));
      ws[kr][q * 4 + 0] = v.x;
      ws[kr][q * 4 + 1] = v.y;
      ws[kr][q * 4 + 2] = v.z;
      ws[kr][q * 4 + 3] = v.w;
    }
    __syncthreads();
#pragma unroll
    for (int kk = 0; kk < 32; ++kk) {
      float4 a = *((const float4*)&xs[kk][ty * 4]);
      float4 b0 = *((const float4*)&ws[kk][tx * 8]);
      float4 b1 = *((const float4*)&ws[kk][tx * 8 + 4]);
      float av[4] = {a.x, a.y, a.z, a.w};
      float bv[8] = {b0.x, b0.y, b0.z, b0.w, b1.x, b1.y, b1.z, b1.w};
#pragma unroll
      for (int r = 0; r < 4; ++r)
#pragma unroll
        for (int c = 0; c < 8; ++c) acc[r][c] = fmaf(av[r], bv[c], acc[r][c]);
    }
    __syncthreads();
  }
#pragma unroll
  for (int r = 0; r < 4; ++r) {
    int grow = row0 + ty * 4 + r;
    if (grow < NN) {
#pragma unroll
      for (int c = 0; c < 8; ++c) {
        int gc = tx * 8 + c;
        float v = acc[r][c] + bias[gc];
        out[(size_t)grow * NH + gc] = fmaxf(v, 0.f);
      }
    }
  }
}

// gemm2: writes h0 as packed bf16 (for propagation) and acc = temp[0]*h in fp32.
__global__ __launch_bounds__(256) void gemm2_kernel(
    const float* __restrict__ X, const float* __restrict__ W,
    const float* __restrict__ bias, u32* __restrict__ hout,
    float* __restrict__ accb, const float* __restrict__ temp) {
  __shared__ float xs[32][68];
  __shared__ float ws[32][132];
  int tid = threadIdx.x;
  int tx = tid & 15;
  int ty = tid >> 4;
  int row0 = blockIdx.x * 64;
  float acc[4][8];
#pragma unroll
  for (int r = 0; r < 4; ++r)
#pragma unroll
    for (int c = 0; c < 8; ++c) acc[r][c] = 0.f;

  for (int k0 = 0; k0 < NH; k0 += 32) {
#pragma unroll
    for (int i = 0; i < 2; ++i) {
      int slot = tid + i * 256;
      int r = slot >> 3;
      int q = slot & 7;
      int grow = row0 + r;
      float4 v = make_float4(0.f, 0.f, 0.f, 0.f);
      if (grow < NN) v = *((const float4*)(X + (size_t)grow * NH + k0 + q * 4));
      xs[q * 4 + 0][r] = v.x;
      xs[q * 4 + 1][r] = v.y;
      xs[q * 4 + 2][r] = v.z;
      xs[q * 4 + 3][r] = v.w;
    }
#pragma unroll
    for (int i = 0; i < 4; ++i) {
      int slot = tid + i * 256;
      int kr = slot >> 5;
      int q = slot & 31;
      float4 v = *((const float4*)(W + (size_t)(k0 + kr) * NH + q * 4));
      ws[kr][q * 4 + 0] = v.x;
      ws[kr][q * 4 + 1] = v.y;
      ws[kr][q * 4 + 2] = v.z;
      ws[kr][q * 4 + 3] = v.w;
    }
    __syncthreads();
#pragma unroll
    for (int kk = 0; kk < 32; ++kk) {
      float4 a = *((const float4*)&xs[kk][ty * 4]);
      float4 b0 = *((const float4*)&ws[kk][tx * 8]);
      float4 b1 = *((const float4*)&ws[kk][tx * 8 + 4]);
      float av[4] = {a.x, a.y, a.z, a.w};
      float bv[8] = {b0.x, b0.y, b0.z, b0.w, b1.x, b1.y, b1.z, b1.w};
#pragma unroll
      for (int r = 0; r < 4; ++r)
#pragma unroll
        for (int c = 0; c < 8; ++c) acc[r][c] = fmaf(av[r], bv[c], acc[r][c]);
    }
    __syncthreads();
  }
  float t0 = temp[0];
#pragma unroll
  for (int r = 0; r < 4; ++r) {
    int grow = row0 + ty * 4 + r;
    if (grow < NN) {
#pragma unroll
      for (int c2 = 0; c2 < 4; ++c2) {
        int gc = tx * 8 + c2 * 2;
        float v0 = acc[r][c2 * 2] + bias[gc];
        float v1 = acc[r][c2 * 2 + 1] + bias[gc + 1];
        hout[(size_t)grow * 64 + tx * 4 + c2] = pack2(v0, v1);
        accb[(size_t)grow * NH + gc] = t0 * v0;
        accb[(size_t)grow * NH + gc + 1] = t0 * v1;
      }
    }
  }
}

// ---------------- Propagation: one wave per node, bf16 features ----------------
// src/dst rows are 128 bf16 = 64 u32; lane l covers features {2l, 2l+1}.

__global__ __launch_bounds__(256) void prop_kernel(
    const u32* __restrict__ src, u32* __restrict__ dst,
    float* __restrict__ acc, const float* __restrict__ dinv,
    const int* __restrict__ colptr, const int2* __restrict__ epack,
    const float* __restrict__ temp, int step, int write_dst) {
  int wave = threadIdx.x >> 6;
  int lane = threadIdx.x & 63;
  int node = blockIdx.x * 4 + wave;
  if (node >= NN) return;
  float gamma = temp[step + 1];
  int beg = colptr[node];
  int end = colptr[node + 1];
  float ax0 = 0.f, ay0 = 0.f, ax1 = 0.f, ay1 = 0.f;
  for (int base = beg; base < end; base += 64) {
    int idx = base + lane;
    int r = 0;
    float wgt = 0.f;
    if (idx < end) {
      int2 p = epack[idx];
      r = p.x;
      r = (r < 0) ? 0 : ((r >= NN) ? NN - 1 : r);
      wgt = __int_as_float(p.y);
    }
    int m = end - base;
    if (m > 64) m = 64;
    int j = 0;
    for (; j + 2 <= m; j += 2) {
      int rj0 = __shfl(r, j);
      float wj0 = __shfl(wgt, j);
      int rj1 = __shfl(r, j + 1);
      float wj1 = __shfl(wgt, j + 1);
      u32 v0 = src[(size_t)rj0 * 64 + lane];
      u32 v1 = src[(size_t)rj1 * 64 + lane];
      ax0 = fmaf(wj0, bf2f(v0 & 0xffffu), ax0);
      ay0 = fmaf(wj0, bf2f(v0 >> 16), ay0);
      ax1 = fmaf(wj1, bf2f(v1 & 0xffffu), ax1);
      ay1 = fmaf(wj1, bf2f(v1 >> 16), ay1);
    }
    if (j < m) {
      int rj = __shfl(r, j);
      float wj = __shfl(wgt, j);
      u32 v = src[(size_t)rj * 64 + lane];
      ax0 = fmaf(wj, bf2f(v & 0xffffu), ax0);
      ay0 = fmaf(wj, bf2f(v >> 16), ay0);
    }
  }
  float ax = ax0 + ax1;
  float ay = ay0 + ay1;
  // self loop
  float di = dinv[node];
  float sw = di * di;
  u32 vs = src[(size_t)node * 64 + lane];
  ax = fmaf(sw, bf2f(vs & 0xffffu), ax);
  ay = fmaf(sw, bf2f(vs >> 16), ay);
  if (write_dst) dst[(size_t)node * 64 + lane] = pack2(ax, ay);
  float2* a2 = (float2*)acc;
  float2 av = a2[(size_t)node * 64 + lane];
  av.x = fmaf(gamma, ax, av.x);
  av.y = fmaf(gamma, ay, av.y);
  a2[(size_t)node * 64 + lane] = av;
}

// ---------------- launch ----------------

extern "C" void kernel_launch(void* const* d_in, const int* in_sizes, int n_in,
                              void* d_out, int out_size, void* d_ws, size_t ws_size,
                              hipStream_t stream) {
  const float* x = (const float*)d_in[0];
  const int* erow_in = (const int*)d_in[1];          // edge_index[0], E ints
  const int* ecol_in = erow_in + NE;                 // edge_index[1]
  const float* W1 = (const float*)d_in[2];
  const float* b1 = (const float*)d_in[3];
  const float* W2 = (const float*)d_in[4];
  const float* b2 = (const float*)d_in[5];
  const float* temp = (const float*)d_in[6];

  char* w = (char*)d_ws;
  size_t o = 0;
  auto alloc = [&](size_t bytes) -> void* {
    void* p = w + o;
    o += (bytes + 255) & ~(size_t)255;
    return p;
  };
  int* cnt = (int*)alloc((size_t)NN * 4);
  int* colptr = (int*)alloc((size_t)(NN + 1) * 4);
  int* cursor = (int*)alloc((size_t)NN * 4);
  float* dinv = (float*)alloc((size_t)NN * 4);
  int2* epack = (int2*)alloc((size_t)NE * 8);
  float* bufH = (float*)alloc((size_t)NN * NH * 4);   // fp32 hidden1
  u32* bufP0 = (u32*)alloc((size_t)NN * 64 * 4);      // bf16 h_k ping
  u32* bufP1 = (u32*)alloc((size_t)NN * 64 * 4);      // bf16 h_k pong
  float* accb = (float*)d_out;                        // fp32 PPR accumulator
  (void)ws_size;

  hipMemsetAsync(cnt, 0, (size_t)NN * 4, stream);

  count_kernel<<<NE / 256, 256, 0, stream>>>(ecol_in, cnt);
  dinv_kernel<<<(NN + 255) / 256, 256, 0, stream>>>(cnt, dinv);
  scan_kernel<<<1, 1024, 0, stream>>>(cnt, colptr, cursor);
  fill_kernel<<<NE / 256, 256, 0, stream>>>(erow_in, ecol_in, dinv, cursor, epack);

  gemm1_kernel<<<(NN + 63) / 64, 256, 0, stream>>>(x, W1, b1, bufH);
  gemm2_kernel<<<(NN + 63) / 64, 256, 0, stream>>>(bufH, W2, b2, bufP0, accb, temp);

  u32* src = bufP0;
  u32* dst = bufP1;
  for (int k = 0; k < NK; ++k) {
    prop_kernel<<<(NN + 3) / 4, 256, 0, stream>>>(src, dst, accb, dinv, colptr, epack,
                                                  temp, k, (k < NK - 1) ? 1 : 0);
    u32* t = src;
    src = dst;
    dst = t;
  }
}

// Round 4
// 1949.604 us; speedup vs baseline: 1.7471x; 1.1602x over previous
//
#include <hip/hip_runtime.h>
#include <hip/hip_fp16.h>

#define NN 100000
#define NE 3200000
#define NF 512
#define NH 128
#define NK 10
#define LDA 40  // f16 LDS row stride (32 + 8 pad): keeps 16B alignment, spreads banks

typedef unsigned int u32;
typedef _Float16 f16;
typedef f16 f16x4 __attribute__((ext_vector_type(4)));
typedef f16 f16x8 __attribute__((ext_vector_type(8)));
typedef float f32x4 __attribute__((ext_vector_type(4)));

__device__ __forceinline__ float2 up2(u32 v) {
  __half2 h = *reinterpret_cast<__half2*>(&v);
  return __half22float2(h);
}
__device__ __forceinline__ u32 pk2(float a, float b) {
  __half2 h = __floats2half2_rn(a, b);
  return *reinterpret_cast<u32*>(&h);
}

// ---------------- CSR build ----------------

__global__ void count_kernel(const int* __restrict__ col, int* __restrict__ cnt) {
  int e = blockIdx.x * 256 + threadIdx.x;
  if (e < NE) atomicAdd(&cnt[col[e]], 1);
}

__global__ void dinv_kernel(const int* __restrict__ cnt, float* __restrict__ dinv) {
  int i = blockIdx.x * 256 + threadIdx.x;
  if (i < NN) dinv[i] = rsqrtf((float)(cnt[i] + 1));
}

// two-level scan: block sums -> scan of 98 sums -> local scan + offset
__global__ __launch_bounds__(256) void bsum_kernel(const int* __restrict__ cnt,
                                                   int* __restrict__ bsum) {
  int b = blockIdx.x;
  int t = threadIdx.x;
  int base = b * 1024;
  int s = 0;
#pragma unroll
  for (int j = 0; j < 4; ++j) {
    int i = base + t + j * 256;
    if (i < NN) s += cnt[i];
  }
  for (int off = 32; off > 0; off >>= 1) s += __shfl_down(s, off);
  __shared__ int wsum[4];
  if ((t & 63) == 0) wsum[t >> 6] = s;
  __syncthreads();
  if (t == 0) bsum[b] = wsum[0] + wsum[1] + wsum[2] + wsum[3];
}

__global__ void scan98_kernel(const int* __restrict__ bsum, int* __restrict__ boff,
                              int* __restrict__ colptr) {
  __shared__ int buf[128];
  int t = threadIdx.x;
  int v = (t < 98) ? bsum[t] : 0;
  buf[t] = v;
  __syncthreads();
  for (int off = 1; off < 128; off <<= 1) {
    int a = (t >= off) ? buf[t - off] : 0;
    __syncthreads();
    buf[t] += a;
    __syncthreads();
  }
  if (t < 98) boff[t] = buf[t] - v;
  if (t == 97) colptr[NN] = buf[t];
}

__global__ __launch_bounds__(1024) void localscan_kernel(const int* __restrict__ cnt,
                                                         const int* __restrict__ boff,
                                                         int* __restrict__ colptr,
                                                         int* __restrict__ cursor) {
  __shared__ int buf[1024];
  int b = blockIdx.x;
  int t = threadIdx.x;
  int i = b * 1024 + t;
  int v = (i < NN) ? cnt[i] : 0;
  buf[t] = v;
  __syncthreads();
  for (int off = 1; off < 1024; off <<= 1) {
    int a = (t >= off) ? buf[t - off] : 0;
    __syncthreads();
    buf[t] += a;
    __syncthreads();
  }
  if (i < NN) {
    int e = boff[b] + buf[t] - v;
    colptr[i] = e;
    cursor[i] = e;
  }
}

__global__ void fill_kernel(const int* __restrict__ row, const int* __restrict__ col,
                            const float* __restrict__ dinv, int* __restrict__ cursor,
                            int2* __restrict__ epack) {
  int e = blockIdx.x * 256 + threadIdx.x;
  if (e >= NE) return;
  int r = row[e], c = col[e];
  int pos = atomicAdd(&cursor[c], 1);
  int2 p;
  p.x = r;
  p.y = __float_as_int(dinv[r] * dinv[c]);
  epack[pos] = p;
}

// ---------------- MFMA GEMMs (f16 inputs, fp32 acc) ----------------
// 128x128 tile, 256 threads = 4 waves; wave w: rows [w*32, w*32+32), 2x8 MFMA tiles.
// A-frag: A[m = lane&15][k = (lane>>4)*8 + j]; B-frag: B[n = lane&15][k = ...].
// C/D: col = lane&15, row = (lane>>4)*4 + reg.

__global__ __launch_bounds__(256) void gemm1_kernel(
    const float* __restrict__ X, const float* __restrict__ W,
    const float* __restrict__ bias, u32* __restrict__ hout) {
  __shared__ f16 smem[16384];  // 32KB: A=[0,5120), B=[5120,10240); out overlaps [0,16384)
  __shared__ float bias_s[NH];
  f16* As = smem;
  f16* Bs = smem + 128 * LDA;
  int tid = threadIdx.x;
  int wave = tid >> 6, lane = tid & 63;
  int quad = lane >> 4, l16 = lane & 15;
  int row0 = blockIdx.x * 128;
  if (tid < NH) bias_s[tid] = bias[tid];

  f32x4 acc[2][8];
#pragma unroll
  for (int t = 0; t < 2; ++t)
#pragma unroll
    for (int u = 0; u < 8; ++u) acc[t][u] = (f32x4){0.f, 0.f, 0.f, 0.f};

  for (int k0 = 0; k0 < NF; k0 += 32) {
    // stage A: 128 rows x 32 k, fp32 -> f16
#pragma unroll
    for (int i = 0; i < 4; ++i) {
      int slot = tid + i * 256;  // 0..1023
      int r = slot >> 3, q4 = slot & 7;
      int grow = row0 + r;
      float4 v = make_float4(0.f, 0.f, 0.f, 0.f);
      if (grow < NN) v = *(const float4*)(X + (size_t)grow * NF + k0 + q4 * 4);
      f16x4 h;
      h[0] = (f16)v.x; h[1] = (f16)v.y; h[2] = (f16)v.z; h[3] = (f16)v.w;
      *(f16x4*)(As + r * LDA + q4 * 4) = h;
    }
    // stage B: W chunk [k0..k0+32) x 128, transposed to [n][k]
#pragma unroll
    for (int i = 0; i < 4; ++i) {
      int slot = tid + i * 256;  // 0..1023
      int n = slot & 127, k4 = slot >> 7;  // k4: 0..7
      f16x4 h;
#pragma unroll
      for (int j = 0; j < 4; ++j) h[j] = (f16)W[(size_t)(k0 + k4 * 4 + j) * NH + n];
      *(f16x4*)(Bs + n * LDA + k4 * 4) = h;
    }
    __syncthreads();
    f16x8 a0 = *(f16x8*)(As + (wave * 32 + l16) * LDA + quad * 8);
    f16x8 a1 = *(f16x8*)(As + (wave * 32 + 16 + l16) * LDA + quad * 8);
#pragma unroll
    for (int u = 0; u < 8; ++u) {
      f16x8 b = *(f16x8*)(Bs + (u * 16 + l16) * LDA + quad * 8);
      acc[0][u] = __builtin_amdgcn_mfma_f32_16x16x32_f16(a0, b, acc[0][u], 0, 0, 0);
      acc[1][u] = __builtin_amdgcn_mfma_f32_16x16x32_f16(a1, b, acc[1][u], 0, 0, 0);
    }
    __syncthreads();
  }
  // epilogue: bias + relu -> f16 LDS, then coalesced copy out
#pragma unroll
  for (int t = 0; t < 2; ++t)
#pragma unroll
    for (int u = 0; u < 8; ++u)
#pragma unroll
      for (int r = 0; r < 4; ++r) {
        int row = wave * 32 + t * 16 + quad * 4 + r;
        int col = u * 16 + l16;
        float v = acc[t][u][r] + bias_s[col];
        smem[row * 128 + col] = (f16)fmaxf(v, 0.f);
      }
  __syncthreads();
  const u32* os = (const u32*)smem;
#pragma unroll
  for (int i = 0; i < 8; ++i) {
    int idx4 = tid + i * 256;  // 0..2047, each = 4 u32
    int row = idx4 >> 4;
    int grow = row0 + row;
    if (grow < NN) {
      uint4 v = *(const uint4*)(os + idx4 * 4);
      *(uint4*)(hout + (size_t)grow * 64 + (idx4 * 4 & 63)) = v;
    }
  }
}

__global__ __launch_bounds__(256) void gemm2_kernel(
    const u32* __restrict__ Xh, const float* __restrict__ W,
    const float* __restrict__ bias, u32* __restrict__ hout) {
  __shared__ f16 smem[16384];
  __shared__ float bias_s[NH];
  f16* As = smem;
  f16* Bs = smem + 128 * LDA;
  int tid = threadIdx.x;
  int wave = tid >> 6, lane = tid & 63;
  int quad = lane >> 4, l16 = lane & 15;
  int row0 = blockIdx.x * 128;
  if (tid < NH) bias_s[tid] = bias[tid];

  f32x4 acc[2][8];
#pragma unroll
  for (int t = 0; t < 2; ++t)
#pragma unroll
    for (int u = 0; u < 8; ++u) acc[t][u] = (f32x4){0.f, 0.f, 0.f, 0.f};

  for (int k0 = 0; k0 < NH; k0 += 32) {
    // stage A: already f16, direct u32x4 copy. 128 rows x 16 u32
#pragma unroll
    for (int i = 0; i < 2; ++i) {
      int slot = tid + i * 256;  // 0..511
      int r = slot >> 2, q = slot & 3;
      int grow = row0 + r;
      uint4 v = make_uint4(0, 0, 0, 0);
      if (grow < NN) v = *(const uint4*)(Xh + (size_t)grow * 64 + (k0 >> 1) + q * 4);
      *(uint4*)(As + r * LDA + q * 8) = v;
    }
#pragma unroll
    for (int i = 0; i < 4; ++i) {
      int slot = tid + i * 256;
      int n = slot & 127, k4 = slot >> 7;
      f16x4 h;
#pragma unroll
      for (int j = 0; j < 4; ++j) h[j] = (f16)W[(size_t)(k0 + k4 * 4 + j) * NH + n];
      *(f16x4*)(Bs + n * LDA + k4 * 4) = h;
    }
    __syncthreads();
    f16x8 a0 = *(f16x8*)(As + (wave * 32 + l16) * LDA + quad * 8);
    f16x8 a1 = *(f16x8*)(As + (wave * 32 + 16 + l16) * LDA + quad * 8);
#pragma unroll
    for (int u = 0; u < 8; ++u) {
      f16x8 b = *(f16x8*)(Bs + (u * 16 + l16) * LDA + quad * 8);
      acc[0][u] = __builtin_amdgcn_mfma_f32_16x16x32_f16(a0, b, acc[0][u], 0, 0, 0);
      acc[1][u] = __builtin_amdgcn_mfma_f32_16x16x32_f16(a1, b, acc[1][u], 0, 0, 0);
    }
    __syncthreads();
  }
#pragma unroll
  for (int t = 0; t < 2; ++t)
#pragma unroll
    for (int u = 0; u < 8; ++u)
#pragma unroll
      for (int r = 0; r < 4; ++r) {
        int row = wave * 32 + t * 16 + quad * 4 + r;
        int col = u * 16 + l16;
        smem[row * 128 + col] = (f16)(acc[t][u][r] + bias_s[col]);
      }
  __syncthreads();
  const u32* os = (const u32*)smem;
#pragma unroll
  for (int i = 0; i < 8; ++i) {
    int idx4 = tid + i * 256;
    int row = idx4 >> 4;
    int grow = row0 + row;
    if (grow < NN) {
      uint4 v = *(const uint4*)(os + idx4 * 4);
      *(uint4*)(hout + (size_t)grow * 64 + (idx4 * 4 & 63)) = v;
    }
  }
}

// ---------------- Propagation: one wave per node, f16 features ----------------
// rows are 128 f16 = 64 u32; lane l covers features {2l, 2l+1}. No acc here.

__global__ __launch_bounds__(256) void prop_kernel(
    const u32* __restrict__ src, u32* __restrict__ dst,
    const float* __restrict__ dinv, const int* __restrict__ colptr,
    const int2* __restrict__ epack) {
  int wave = threadIdx.x >> 6;
  int lane = threadIdx.x & 63;
  int node = blockIdx.x * 4 + wave;
  if (node >= NN) return;
  int beg = colptr[node];
  int end = colptr[node + 1];
  float ax0 = 0.f, ay0 = 0.f, ax1 = 0.f, ay1 = 0.f;
  for (int base = beg; base < end; base += 64) {
    int idx = base + lane;
    int r = 0;
    float wgt = 0.f;
    if (idx < end) {
      int2 p = epack[idx];
      r = p.x;
      r = (r < 0) ? 0 : ((r >= NN) ? NN - 1 : r);
      wgt = __int_as_float(p.y);
    }
    int m = end - base;
    if (m > 64) m = 64;
    int j = 0;
    for (; j + 2 <= m; j += 2) {
      int rj0 = __shfl(r, j);
      float wj0 = __shfl(wgt, j);
      int rj1 = __shfl(r, j + 1);
      float wj1 = __shfl(wgt, j + 1);
      float2 v0 = up2(src[(size_t)rj0 * 64 + lane]);
      float2 v1 = up2(src[(size_t)rj1 * 64 + lane]);
      ax0 = fmaf(wj0, v0.x, ax0);
      ay0 = fmaf(wj0, v0.y, ay0);
      ax1 = fmaf(wj1, v1.x, ax1);
      ay1 = fmaf(wj1, v1.y, ay1);
    }
    if (j < m) {
      int rj = __shfl(r, j);
      float wj = __shfl(wgt, j);
      float2 v = up2(src[(size_t)rj * 64 + lane]);
      ax0 = fmaf(wj, v.x, ax0);
      ay0 = fmaf(wj, v.y, ay0);
    }
  }
  float ax = ax0 + ax1;
  float ay = ay0 + ay1;
  float di = dinv[node];
  float sw = di * di;
  float2 vs = up2(src[(size_t)node * 64 + lane]);
  ax = fmaf(sw, vs.x, ax);
  ay = fmaf(sw, vs.y, ay);
  dst[(size_t)node * 64 + lane] = pk2(ax, ay);
}

// ---------------- fused weighted sums ----------------

__global__ void sum6_kernel(const u32* __restrict__ b0, const u32* __restrict__ b1,
                            const u32* __restrict__ b2, const u32* __restrict__ b3,
                            const u32* __restrict__ b4, const u32* __restrict__ b5,
                            const float* __restrict__ temp, float* __restrict__ out) {
  int i = blockIdx.x * 256 + threadIdx.x;  // < NN*64 exactly
  float2 s = make_float2(0.f, 0.f);
  float2 v;
  v = up2(b0[i]); s.x = fmaf(temp[0], v.x, s.x); s.y = fmaf(temp[0], v.y, s.y);
  v = up2(b1[i]); s.x = fmaf(temp[1], v.x, s.x); s.y = fmaf(temp[1], v.y, s.y);
  v = up2(b2[i]); s.x = fmaf(temp[2], v.x, s.x); s.y = fmaf(temp[2], v.y, s.y);
  v = up2(b3[i]); s.x = fmaf(temp[3], v.x, s.x); s.y = fmaf(temp[3], v.y, s.y);
  v = up2(b4[i]); s.x = fmaf(temp[4], v.x, s.x); s.y = fmaf(temp[4], v.y, s.y);
  v = up2(b5[i]); s.x = fmaf(temp[5], v.x, s.x); s.y = fmaf(temp[5], v.y, s.y);
  ((float2*)out)[i] = s;
}

__global__ void sum5_kernel(const u32* __restrict__ b0, const u32* __restrict__ b1,
                            const u32* __restrict__ b2, const u32* __restrict__ b3,
                            const u32* __restrict__ b4,
                            const float* __restrict__ temp, float* __restrict__ out) {
  int i = blockIdx.x * 256 + threadIdx.x;
  float2 s = ((float2*)out)[i];
  float2 v;
  v = up2(b0[i]); s.x = fmaf(temp[6], v.x, s.x); s.y = fmaf(temp[6], v.y, s.y);
  v = up2(b1[i]); s.x = fmaf(temp[7], v.x, s.x); s.y = fmaf(temp[7], v.y, s.y);
  v = up2(b2[i]); s.x = fmaf(temp[8], v.x, s.x); s.y = fmaf(temp[8], v.y, s.y);
  v = up2(b3[i]); s.x = fmaf(temp[9], v.x, s.x); s.y = fmaf(temp[9], v.y, s.y);
  v = up2(b4[i]); s.x = fmaf(temp[10], v.x, s.x); s.y = fmaf(temp[10], v.y, s.y);
  ((float2*)out)[i] = s;
}

// ---------------- launch ----------------

extern "C" void kernel_launch(void* const* d_in, const int* in_sizes, int n_in,
                              void* d_out, int out_size, void* d_ws, size_t ws_size,
                              hipStream_t stream) {
  const float* x = (const float*)d_in[0];
  const int* erow_in = (const int*)d_in[1];
  const int* ecol_in = erow_in + NE;
  const float* W1 = (const float*)d_in[2];
  const float* b1 = (const float*)d_in[3];
  const float* W2 = (const float*)d_in[4];
  const float* b2 = (const float*)d_in[5];
  const float* temp = (const float*)d_in[6];

  char* w = (char*)d_ws;
  size_t o = 0;
  auto alloc = [&](size_t bytes) -> void* {
    void* p = w + o;
    o += (bytes + 255) & ~(size_t)255;
    return p;
  };
  int* cnt = (int*)alloc((size_t)NN * 4);
  int* colptr = (int*)alloc((size_t)(NN + 1) * 4);
  int* cursor = (int*)alloc((size_t)NN * 4);
  float* dinv = (float*)alloc((size_t)NN * 4);
  int* bsum = (int*)alloc(128 * 4);
  int* boff = (int*)alloc(128 * 4);
  int2* epack = (int2*)alloc((size_t)NE * 8);
  u32* bufA = (u32*)alloc((size_t)NN * 64 * 4);  // h1 (gemm1 out), later h5
  u32* B[5];
  for (int i = 0; i < 5; ++i) B[i] = (u32*)alloc((size_t)NN * 64 * 4);
  float* outp = (float*)d_out;
  (void)ws_size;

  hipMemsetAsync(cnt, 0, (size_t)NN * 4, stream);
  count_kernel<<<NE / 256, 256, 0, stream>>>(ecol_in, cnt);
  dinv_kernel<<<(NN + 255) / 256, 256, 0, stream>>>(cnt, dinv);
  bsum_kernel<<<98, 256, 0, stream>>>(cnt, bsum);
  scan98_kernel<<<1, 128, 0, stream>>>(bsum, boff, colptr);
  localscan_kernel<<<98, 1024, 0, stream>>>(cnt, boff, colptr, cursor);
  fill_kernel<<<NE / 256, 256, 0, stream>>>(erow_in, ecol_in, dinv, cursor, epack);

  int gblocks = (NN + 127) / 128;
  gemm1_kernel<<<gblocks, 256, 0, stream>>>(x, W1, b1, bufA);
  gemm2_kernel<<<gblocks, 256, 0, stream>>>(bufA, W2, b2, B[0]);  // B0 = h0

  int pblocks = (NN + 3) / 4;
  // steps 1..5: B0->B1->B2->B3->B4->A
  prop_kernel<<<pblocks, 256, 0, stream>>>(B[0], B[1], dinv, colptr, epack);
  prop_kernel<<<pblocks, 256, 0, stream>>>(B[1], B[2], dinv, colptr, epack);
  prop_kernel<<<pblocks, 256, 0, stream>>>(B[2], B[3], dinv, colptr, epack);
  prop_kernel<<<pblocks, 256, 0, stream>>>(B[3], B[4], dinv, colptr, epack);
  prop_kernel<<<pblocks, 256, 0, stream>>>(B[4], bufA, dinv, colptr, epack);
  sum6_kernel<<<NN * 64 / 256, 256, 0, stream>>>(B[0], B[1], B[2], B[3], B[4], bufA,
                                                 temp, outp);
  // steps 6..10: A->B0->B1->B2->B3->B4
  prop_kernel<<<pblocks, 256, 0, stream>>>(bufA, B[0], dinv, colptr, epack);
  prop_kernel<<<pblocks, 256, 0, stream>>>(B[0], B[1], dinv, colptr, epack);
  prop_kernel<<<pblocks, 256, 0, stream>>>(B[1], B[2], dinv, colptr, epack);
  prop_kernel<<<pblocks, 256, 0, stream>>>(B[2], B[3], dinv, colptr, epack);
  prop_kernel<<<pblocks, 256, 0, stream>>>(B[3], B[4], dinv, colptr, epack);
  sum5_kernel<<<NN * 64 / 256, 256, 0, stream>>>(B[0], B[1], B[2], B[3], B[4], temp,
                                                 outp);
}

// Round 5
// 1787.145 us; speedup vs baseline: 1.9060x; 1.0909x over previous
//
#include <hip/hip_runtime.h>
#include <hip/hip_fp16.h>

#define NN 100000
#define NE 3200000
#define NF 512
#define NH 128
#define NK 10
#define LDA 40  // f16 LDS row stride (32 + 8 pad)

typedef unsigned int u32;
typedef _Float16 f16;
typedef f16 f16x4 __attribute__((ext_vector_type(4)));
typedef f16 f16x8 __attribute__((ext_vector_type(8)));
typedef float f32x4 __attribute__((ext_vector_type(4)));

__device__ __forceinline__ float2 up2(u32 v) {
  __half2 h = *reinterpret_cast<__half2*>(&v);
  return __half22float2(h);
}
__device__ __forceinline__ u32 pk2(float a, float b) {
  __half2 h = __floats2half2_rn(a, b);
  return *reinterpret_cast<u32*>(&h);
}

// ---------------- CSR build ----------------
// count/fill use XCD-residue partitioning: block b handles edge chunk b>>3,
// only edges with col/12500 == (b&7). With %8 round-robin block->XCD mapping
// each XCD's L2 owns a disjoint slice of cnt/cursor/epack -> no line bouncing.
// Correct regardless of actual mapping (atomics are device-scope).

__global__ void count_kernel(const int* __restrict__ col, int* __restrict__ cnt) {
  int chunk = blockIdx.x >> 3;
  int res = blockIdx.x & 7;
  int e = chunk * 256 + threadIdx.x;
  if (e >= NE) return;
  int c = col[e];
  if ((int)((u32)c / 12500u) != res) return;
  atomicAdd(&cnt[c], 1);
}

__global__ void dinv_kernel(const int* __restrict__ cnt, float* __restrict__ dinv) {
  int i = blockIdx.x * 256 + threadIdx.x;
  if (i < NN) dinv[i] = rsqrtf((float)(cnt[i] + 1));
}

__global__ __launch_bounds__(256) void bsum_kernel(const int* __restrict__ cnt,
                                                   int* __restrict__ bsum) {
  int b = blockIdx.x;
  int t = threadIdx.x;
  int base = b * 1024;
  int s = 0;
#pragma unroll
  for (int j = 0; j < 4; ++j) {
    int i = base + t + j * 256;
    if (i < NN) s += cnt[i];
  }
  for (int off = 32; off > 0; off >>= 1) s += __shfl_down(s, off);
  __shared__ int wsum[4];
  if ((t & 63) == 0) wsum[t >> 6] = s;
  __syncthreads();
  if (t == 0) bsum[b] = wsum[0] + wsum[1] + wsum[2] + wsum[3];
}

__global__ void scan98_kernel(const int* __restrict__ bsum, int* __restrict__ boff,
                              int* __restrict__ colptr) {
  __shared__ int buf[128];
  int t = threadIdx.x;
  int v = (t < 98) ? bsum[t] : 0;
  buf[t] = v;
  __syncthreads();
  for (int off = 1; off < 128; off <<= 1) {
    int a = (t >= off) ? buf[t - off] : 0;
    __syncthreads();
    buf[t] += a;
    __syncthreads();
  }
  if (t < 98) boff[t] = buf[t] - v;
  if (t == 97) colptr[NN] = buf[t];
}

__global__ __launch_bounds__(1024) void localscan_kernel(const int* __restrict__ cnt,
                                                         const int* __restrict__ boff,
                                                         int* __restrict__ colptr,
                                                         int* __restrict__ cursor) {
  __shared__ int buf[1024];
  int b = blockIdx.x;
  int t = threadIdx.x;
  int i = b * 1024 + t;
  int v = (i < NN) ? cnt[i] : 0;
  buf[t] = v;
  __syncthreads();
  for (int off = 1; off < 1024; off <<= 1) {
    int a = (t >= off) ? buf[t - off] : 0;
    __syncthreads();
    buf[t] += a;
    __syncthreads();
  }
  if (i < NN) {
    int e = boff[b] + buf[t] - v;
    colptr[i] = e;
    cursor[i] = e;
  }
}

__global__ void fill_kernel(const int* __restrict__ row, const int* __restrict__ col,
                            const float* __restrict__ dinv, int* __restrict__ cursor,
                            int2* __restrict__ epack) {
  int chunk = blockIdx.x >> 3;
  int res = blockIdx.x & 7;
  int e = chunk * 256 + threadIdx.x;
  if (e >= NE) return;
  int c = col[e];
  if ((int)((u32)c / 12500u) != res) return;
  int r = row[e];
  int pos = atomicAdd(&cursor[c], 1);
  int2 p;
  p.x = r;
  p.y = __float_as_int(dinv[r] * dinv[c]);
  epack[pos] = p;
}

// ---------------- MFMA GEMMs (f16 inputs, fp32 acc) ----------------

__global__ __launch_bounds__(256) void gemm1_kernel(
    const float* __restrict__ X, const float* __restrict__ W,
    const float* __restrict__ bias, u32* __restrict__ hout) {
  __shared__ f16 smem[16384];
  __shared__ float bias_s[NH];
  f16* As = smem;
  f16* Bs = smem + 128 * LDA;
  int tid = threadIdx.x;
  int wave = tid >> 6, lane = tid & 63;
  int quad = lane >> 4, l16 = lane & 15;
  int row0 = blockIdx.x * 128;
  if (tid < NH) bias_s[tid] = bias[tid];

  f32x4 acc[2][8];
#pragma unroll
  for (int t = 0; t < 2; ++t)
#pragma unroll
    for (int u = 0; u < 8; ++u) acc[t][u] = (f32x4){0.f, 0.f, 0.f, 0.f};

  for (int k0 = 0; k0 < NF; k0 += 32) {
#pragma unroll
    for (int i = 0; i < 4; ++i) {
      int slot = tid + i * 256;
      int r = slot >> 3, q4 = slot & 7;
      int grow = row0 + r;
      float4 v = make_float4(0.f, 0.f, 0.f, 0.f);
      if (grow < NN) v = *(const float4*)(X + (size_t)grow * NF + k0 + q4 * 4);
      f16x4 h;
      h[0] = (f16)v.x; h[1] = (f16)v.y; h[2] = (f16)v.z; h[3] = (f16)v.w;
      *(f16x4*)(As + r * LDA + q4 * 4) = h;
    }
#pragma unroll
    for (int i = 0; i < 4; ++i) {
      int slot = tid + i * 256;
      int n = slot & 127, k4 = slot >> 7;
      f16x4 h;
#pragma unroll
      for (int j = 0; j < 4; ++j) h[j] = (f16)W[(size_t)(k0 + k4 * 4 + j) * NH + n];
      *(f16x4*)(Bs + n * LDA + k4 * 4) = h;
    }
    __syncthreads();
    f16x8 a0 = *(f16x8*)(As + (wave * 32 + l16) * LDA + quad * 8);
    f16x8 a1 = *(f16x8*)(As + (wave * 32 + 16 + l16) * LDA + quad * 8);
#pragma unroll
    for (int u = 0; u < 8; ++u) {
      f16x8 b = *(f16x8*)(Bs + (u * 16 + l16) * LDA + quad * 8);
      acc[0][u] = __builtin_amdgcn_mfma_f32_16x16x32_f16(a0, b, acc[0][u], 0, 0, 0);
      acc[1][u] = __builtin_amdgcn_mfma_f32_16x16x32_f16(a1, b, acc[1][u], 0, 0, 0);
    }
    __syncthreads();
  }
#pragma unroll
  for (int t = 0; t < 2; ++t)
#pragma unroll
    for (int u = 0; u < 8; ++u)
#pragma unroll
      for (int r = 0; r < 4; ++r) {
        int row = wave * 32 + t * 16 + quad * 4 + r;
        int col = u * 16 + l16;
        float v = acc[t][u][r] + bias_s[col];
        smem[row * 128 + col] = (f16)fmaxf(v, 0.f);
      }
  __syncthreads();
  const u32* os = (const u32*)smem;
#pragma unroll
  for (int i = 0; i < 8; ++i) {
    int idx4 = tid + i * 256;
    int row = idx4 >> 4;
    int grow = row0 + row;
    if (grow < NN) {
      uint4 v = *(const uint4*)(os + idx4 * 4);
      *(uint4*)(hout + (size_t)grow * 64 + (idx4 * 4 & 63)) = v;
    }
  }
}

__global__ __launch_bounds__(256) void gemm2_kernel(
    const u32* __restrict__ Xh, const float* __restrict__ W,
    const float* __restrict__ bias, u32* __restrict__ hout) {
  __shared__ f16 smem[16384];
  __shared__ float bias_s[NH];
  f16* As = smem;
  f16* Bs = smem + 128 * LDA;
  int tid = threadIdx.x;
  int wave = tid >> 6, lane = tid & 63;
  int quad = lane >> 4, l16 = lane & 15;
  int row0 = blockIdx.x * 128;
  if (tid < NH) bias_s[tid] = bias[tid];

  f32x4 acc[2][8];
#pragma unroll
  for (int t = 0; t < 2; ++t)
#pragma unroll
    for (int u = 0; u < 8; ++u) acc[t][u] = (f32x4){0.f, 0.f, 0.f, 0.f};

  for (int k0 = 0; k0 < NH; k0 += 32) {
#pragma unroll
    for (int i = 0; i < 2; ++i) {
      int slot = tid + i * 256;
      int r = slot >> 2, q = slot & 3;
      int grow = row0 + r;
      uint4 v = make_uint4(0, 0, 0, 0);
      if (grow < NN) v = *(const uint4*)(Xh + (size_t)grow * 64 + (k0 >> 1) + q * 4);
      *(uint4*)(As + r * LDA + q * 8) = v;
    }
#pragma unroll
    for (int i = 0; i < 4; ++i) {
      int slot = tid + i * 256;
      int n = slot & 127, k4 = slot >> 7;
      f16x4 h;
#pragma unroll
      for (int j = 0; j < 4; ++j) h[j] = (f16)W[(size_t)(k0 + k4 * 4 + j) * NH + n];
      *(f16x4*)(Bs + n * LDA + k4 * 4) = h;
    }
    __syncthreads();
    f16x8 a0 = *(f16x8*)(As + (wave * 32 + l16) * LDA + quad * 8);
    f16x8 a1 = *(f16x8*)(As + (wave * 32 + 16 + l16) * LDA + quad * 8);
#pragma unroll
    for (int u = 0; u < 8; ++u) {
      f16x8 b = *(f16x8*)(Bs + (u * 16 + l16) * LDA + quad * 8);
      acc[0][u] = __builtin_amdgcn_mfma_f32_16x16x32_f16(a0, b, acc[0][u], 0, 0, 0);
      acc[1][u] = __builtin_amdgcn_mfma_f32_16x16x32_f16(a1, b, acc[1][u], 0, 0, 0);
    }
    __syncthreads();
  }
#pragma unroll
  for (int t = 0; t < 2; ++t)
#pragma unroll
    for (int u = 0; u < 8; ++u)
#pragma unroll
      for (int r = 0; r < 4; ++r) {
        int row = wave * 32 + t * 16 + quad * 4 + r;
        int col = u * 16 + l16;
        smem[row * 128 + col] = (f16)(acc[t][u][r] + bias_s[col]);
      }
  __syncthreads();
  const u32* os = (const u32*)smem;
#pragma unroll
  for (int i = 0; i < 8; ++i) {
    int idx4 = tid + i * 256;
    int row = idx4 >> 4;
    int grow = row0 + row;
    if (grow < NN) {
      uint4 v = *(const uint4*)(os + idx4 * 4);
      *(uint4*)(hout + (size_t)grow * 64 + (idx4 * 4 & 63)) = v;
    }
  }
}

// ---------------- Propagation ----------------
// One wave per node; 4 edge-groups of 16 lanes. Each group processes one edge
// at a time: lane (g,l) loads uint4 = 16B of the 256B source row -> one
// wave-level load instruction covers 4 edges (1KB in flight per vmcnt slot).
// Per-group partial sums (8 fp32/lane) reduced via shfl_xor(16,32) at the end.

__global__ __launch_bounds__(256) void prop_kernel(
    const u32* __restrict__ src, u32* __restrict__ dst,
    const float* __restrict__ dinv, const int* __restrict__ colptr,
    const int2* __restrict__ epack) {
  int wave = threadIdx.x >> 6;
  int lane = threadIdx.x & 63;
  int g = lane >> 4;
  int l = lane & 15;
  int node = blockIdx.x * 4 + wave;
  if (node >= NN) return;
  int beg = colptr[node];
  int end = colptr[node + 1];
  const uint4* s4 = (const uint4*)src;
  float acc[8];
#pragma unroll
  for (int i = 0; i < 8; ++i) acc[i] = 0.f;

  for (int base = beg; base < end; base += 64) {
    int idx = base + lane;
    int r = 0;
    float wgt = 0.f;
    if (idx < end) {
      int2 p = epack[idx];
      r = p.x;
      r = (r < 0) ? 0 : ((r >= NN) ? NN - 1 : r);
      wgt = __int_as_float(p.y);
    }
    int m = end - base;
    if (m > 64) m = 64;
    int full = m >> 2;
    int j = 0;
    for (; j + 2 <= full; j += 2) {
      int rj0 = __shfl(r, j * 4 + g);
      float wj0 = __shfl(wgt, j * 4 + g);
      int rj1 = __shfl(r, j * 4 + 4 + g);
      float wj1 = __shfl(wgt, j * 4 + 4 + g);
      uint4 v0 = s4[(size_t)rj0 * 16 + l];
      uint4 v1 = s4[(size_t)rj1 * 16 + l];
      float2 f;
      f = up2(v0.x); acc[0] = fmaf(wj0, f.x, acc[0]); acc[1] = fmaf(wj0, f.y, acc[1]);
      f = up2(v0.y); acc[2] = fmaf(wj0, f.x, acc[2]); acc[3] = fmaf(wj0, f.y, acc[3]);
      f = up2(v0.z); acc[4] = fmaf(wj0, f.x, acc[4]); acc[5] = fmaf(wj0, f.y, acc[5]);
      f = up2(v0.w); acc[6] = fmaf(wj0, f.x, acc[6]); acc[7] = fmaf(wj0, f.y, acc[7]);
      f = up2(v1.x); acc[0] = fmaf(wj1, f.x, acc[0]); acc[1] = fmaf(wj1, f.y, acc[1]);
      f = up2(v1.y); acc[2] = fmaf(wj1, f.x, acc[2]); acc[3] = fmaf(wj1, f.y, acc[3]);
      f = up2(v1.z); acc[4] = fmaf(wj1, f.x, acc[4]); acc[5] = fmaf(wj1, f.y, acc[5]);
      f = up2(v1.w); acc[6] = fmaf(wj1, f.x, acc[6]); acc[7] = fmaf(wj1, f.y, acc[7]);
    }
    if (j < full) {
      int rj = __shfl(r, j * 4 + g);
      float wj = __shfl(wgt, j * 4 + g);
      uint4 v = s4[(size_t)rj * 16 + l];
      float2 f;
      f = up2(v.x); acc[0] = fmaf(wj, f.x, acc[0]); acc[1] = fmaf(wj, f.y, acc[1]);
      f = up2(v.y); acc[2] = fmaf(wj, f.x, acc[2]); acc[3] = fmaf(wj, f.y, acc[3]);
      f = up2(v.z); acc[4] = fmaf(wj, f.x, acc[4]); acc[5] = fmaf(wj, f.y, acc[5]);
      f = up2(v.w); acc[6] = fmaf(wj, f.x, acc[6]); acc[7] = fmaf(wj, f.y, acc[7]);
    }
    int rem = m & 3;
    if (rem) {
      // shfl BEFORE the divergent guard (bpermute reads regs regardless of exec)
      int rj = __shfl(r, full * 4 + g);
      float wj = __shfl(wgt, full * 4 + g);
      if (g < rem) {
        uint4 v = s4[(size_t)rj * 16 + l];
        float2 f;
        f = up2(v.x); acc[0] = fmaf(wj, f.x, acc[0]); acc[1] = fmaf(wj, f.y, acc[1]);
        f = up2(v.y); acc[2] = fmaf(wj, f.x, acc[2]); acc[3] = fmaf(wj, f.y, acc[3]);
        f = up2(v.z); acc[4] = fmaf(wj, f.x, acc[4]); acc[5] = fmaf(wj, f.y, acc[5]);
        f = up2(v.w); acc[6] = fmaf(wj, f.x, acc[6]); acc[7] = fmaf(wj, f.y, acc[7]);
      }
    }
  }
  // self loop (group 0 only; added once, then summed into all groups' lanes)
  float di = dinv[node];
  float sw = di * di;
  if (g == 0) {
    uint4 v = s4[(size_t)node * 16 + l];
    float2 f;
    f = up2(v.x); acc[0] = fmaf(sw, f.x, acc[0]); acc[1] = fmaf(sw, f.y, acc[1]);
    f = up2(v.y); acc[2] = fmaf(sw, f.x, acc[2]); acc[3] = fmaf(sw, f.y, acc[3]);
    f = up2(v.z); acc[4] = fmaf(sw, f.x, acc[4]); acc[5] = fmaf(sw, f.y, acc[5]);
    f = up2(v.w); acc[6] = fmaf(sw, f.x, acc[6]); acc[7] = fmaf(sw, f.y, acc[7]);
  }
#pragma unroll
  for (int i = 0; i < 8; ++i) {
    acc[i] += __shfl_xor(acc[i], 16);
    acc[i] += __shfl_xor(acc[i], 32);
  }
  if (g == 0) {
    uint4 o;
    o.x = pk2(acc[0], acc[1]);
    o.y = pk2(acc[2], acc[3]);
    o.z = pk2(acc[4], acc[5]);
    o.w = pk2(acc[6], acc[7]);
    ((uint4*)dst)[(size_t)node * 16 + l] = o;
  }
}

// ---------------- fused weighted sums ----------------

__global__ void sum6_kernel(const u32* __restrict__ b0, const u32* __restrict__ b1,
                            const u32* __restrict__ b2, const u32* __restrict__ b3,
                            const u32* __restrict__ b4, const u32* __restrict__ b5,
                            const float* __restrict__ temp, float* __restrict__ out) {
  int i = blockIdx.x * 256 + threadIdx.x;
  float2 s = make_float2(0.f, 0.f);
  float2 v;
  v = up2(b0[i]); s.x = fmaf(temp[0], v.x, s.x); s.y = fmaf(temp[0], v.y, s.y);
  v = up2(b1[i]); s.x = fmaf(temp[1], v.x, s.x); s.y = fmaf(temp[1], v.y, s.y);
  v = up2(b2[i]); s.x = fmaf(temp[2], v.x, s.x); s.y = fmaf(temp[2], v.y, s.y);
  v = up2(b3[i]); s.x = fmaf(temp[3], v.x, s.x); s.y = fmaf(temp[3], v.y, s.y);
  v = up2(b4[i]); s.x = fmaf(temp[4], v.x, s.x); s.y = fmaf(temp[4], v.y, s.y);
  v = up2(b5[i]); s.x = fmaf(temp[5], v.x, s.x); s.y = fmaf(temp[5], v.y, s.y);
  ((float2*)out)[i] = s;
}

__global__ void sum5_kernel(const u32* __restrict__ b0, const u32* __restrict__ b1,
                            const u32* __restrict__ b2, const u32* __restrict__ b3,
                            const u32* __restrict__ b4,
                            const float* __restrict__ temp, float* __restrict__ out) {
  int i = blockIdx.x * 256 + threadIdx.x;
  float2 s = ((float2*)out)[i];
  float2 v;
  v = up2(b0[i]); s.x = fmaf(temp[6], v.x, s.x); s.y = fmaf(temp[6], v.y, s.y);
  v = up2(b1[i]); s.x = fmaf(temp[7], v.x, s.x); s.y = fmaf(temp[7], v.y, s.y);
  v = up2(b2[i]); s.x = fmaf(temp[8], v.x, s.x); s.y = fmaf(temp[8], v.y, s.y);
  v = up2(b3[i]); s.x = fmaf(temp[9], v.x, s.x); s.y = fmaf(temp[9], v.y, s.y);
  v = up2(b4[i]); s.x = fmaf(temp[10], v.x, s.x); s.y = fmaf(temp[10], v.y, s.y);
  ((float2*)out)[i] = s;
}

// ---------------- launch ----------------

extern "C" void kernel_launch(void* const* d_in, const int* in_sizes, int n_in,
                              void* d_out, int out_size, void* d_ws, size_t ws_size,
                              hipStream_t stream) {
  const float* x = (const float*)d_in[0];
  const int* erow_in = (const int*)d_in[1];
  const int* ecol_in = erow_in + NE;
  const float* W1 = (const float*)d_in[2];
  const float* b1 = (const float*)d_in[3];
  const float* W2 = (const float*)d_in[4];
  const float* b2 = (const float*)d_in[5];
  const float* temp = (const float*)d_in[6];

  char* w = (char*)d_ws;
  size_t o = 0;
  auto alloc = [&](size_t bytes) -> void* {
    void* p = w + o;
    o += (bytes + 255) & ~(size_t)255;
    return p;
  };
  int* cnt = (int*)alloc((size_t)NN * 4);
  int* colptr = (int*)alloc((size_t)(NN + 1) * 4);
  int* cursor = (int*)alloc((size_t)NN * 4);
  float* dinv = (float*)alloc((size_t)NN * 4);
  int* bsum = (int*)alloc(128 * 4);
  int* boff = (int*)alloc(128 * 4);
  int2* epack = (int2*)alloc((size_t)NE * 8);
  u32* bufA = (u32*)alloc((size_t)NN * 64 * 4);
  u32* B[5];
  for (int i = 0; i < 5; ++i) B[i] = (u32*)alloc((size_t)NN * 64 * 4);
  float* outp = (float*)d_out;
  (void)ws_size;

  hipMemsetAsync(cnt, 0, (size_t)NN * 4, stream);
  count_kernel<<<(NE / 256) * 8, 256, 0, stream>>>(ecol_in, cnt);
  dinv_kernel<<<(NN + 255) / 256, 256, 0, stream>>>(cnt, dinv);
  bsum_kernel<<<98, 256, 0, stream>>>(cnt, bsum);
  scan98_kernel<<<1, 128, 0, stream>>>(bsum, boff, colptr);
  localscan_kernel<<<98, 1024, 0, stream>>>(cnt, boff, colptr, cursor);
  fill_kernel<<<(NE / 256) * 8, 256, 0, stream>>>(erow_in, ecol_in, dinv, cursor,
                                                  epack);

  int gblocks = (NN + 127) / 128;
  gemm1_kernel<<<gblocks, 256, 0, stream>>>(x, W1, b1, bufA);
  gemm2_kernel<<<gblocks, 256, 0, stream>>>(bufA, W2, b2, B[0]);

  int pblocks = (NN + 3) / 4;
  prop_kernel<<<pblocks, 256, 0, stream>>>(B[0], B[1], dinv, colptr, epack);
  prop_kernel<<<pblocks, 256, 0, stream>>>(B[1], B[2], dinv, colptr, epack);
  prop_kernel<<<pblocks, 256, 0, stream>>>(B[2], B[3], dinv, colptr, epack);
  prop_kernel<<<pblocks, 256, 0, stream>>>(B[3], B[4], dinv, colptr, epack);
  prop_kernel<<<pblocks, 256, 0, stream>>>(B[4], bufA, dinv, colptr, epack);
  sum6_kernel<<<NN * 64 / 256, 256, 0, stream>>>(B[0], B[1], B[2], B[3], B[4], bufA,
                                                 temp, outp);
  prop_kernel<<<pblocks, 256, 0, stream>>>(bufA, B[0], dinv, colptr, epack);
  prop_kernel<<<pblocks, 256, 0, stream>>>(B[0], B[1], dinv, colptr, epack);
  prop_kernel<<<pblocks, 256, 0, stream>>>(B[1], B[2], dinv, colptr, epack);
  prop_kernel<<<pblocks, 256, 0, stream>>>(B[2], B[3], dinv, colptr, epack);
  prop_kernel<<<pblocks, 256, 0, stream>>>(B[3], B[4], dinv, colptr, epack);
  sum5_kernel<<<NN * 64 / 256, 256, 0, stream>>>(B[0], B[1], B[2], B[3], B[4], temp,
                                                 outp);
}